// Round 2
// baseline (265.708 us; speedup 1.0000x reference)
//
#include <hip/hip_runtime.h>

// Depthwise 3x3 conv (diagonal-masked dense conv), fp32.
// x: (S*B=32, C=256, H=64, W=64)  W: (256,256,3,3) -> only diag [c,c,:,:] used.
//
// Register-sliding-window version, NO LDS:
//  - one wave per (n,c) plane; 64 lanes = 16 column-chunks (float4) x 4 row-blocks
//  - lane owns a 4-column strip over 16 rows; 3-row float4 window slides down
//  - horizontal halo via __shfl from neighbor lane (no LDS, no bank conflicts)
//  - per output row per lane: 1 float4 load, 1 float4 store, 2 shuffles, 36 FMA
// Every global float read once (tiny row-halo overlap absorbed by L1/L2),
// written once. No __syncthreads anywhere -> pure stream at HBM roofline.

#define C_CH 256
#define H_SP 64
#define W_SP 64
#define PLANE (H_SP * W_SP) // 4096 floats

__global__ __launch_bounds__(256, 4) void dwconv3x3_reg(
    const float* __restrict__ x,
    const float* __restrict__ Wfull,
    float* __restrict__ out)
{
    const int tid  = threadIdx.x;
    const int wid  = tid >> 6;          // wave within block: 0..3
    const int lane = tid & 63;
    const int g    = lane >> 4;         // row-block 0..3 (rows 16g .. 16g+15)
    const int cx   = lane & 15;         // float4 chunk within row
    const int col0 = cx << 2;           // first column of this lane's strip
    const int r0   = g << 4;            // first row of this lane's block

    const int p = (blockIdx.x << 2) + wid;   // plane index [0, 8192)
    const int c = p & (C_CH - 1);            // channel (inner leading dim)

    const float* __restrict__ xp = x + (size_t)p * PLANE;
    float* __restrict__ op       = out + (size_t)p * PLANE;

    // 9 diagonal weights, wave-uniform: W[((c*C + c)*3 + kh)*3 + kw]
    const float* __restrict__ wp = Wfull + (size_t)c * (C_CH + 1) * 9;
    const float w00 = wp[0], w01 = wp[1], w02 = wp[2];
    const float w10 = wp[3], w11 = wp[4], w12 = wp[5];
    const float w20 = wp[6], w21 = wp[7], w22 = wp[8];

    // Load one input row's float4 for this lane's strip; zero outside plane.
    auto loadrow = [&](int h) -> float4 {
        if (h >= 0 && h < H_SP)
            return *(const float4*)(xp + h * W_SP + col0);
        return make_float4(0.f, 0.f, 0.f, 0.f);
    };

    // Left/right halo scalars from neighbor lanes (same row, chunk +/- 1).
    // Lane with cx==0 / cx==15 sits at the plane edge -> halo is zero; this
    // also discards the garbage pulled across row-block boundaries.
    auto halo = [&](const float4& v, float& m, float& q) {
        m = __shfl_up(v.w, 1);
        q = __shfl_down(v.x, 1);
        if (cx == 0)  m = 0.f;
        if (cx == 15) q = 0.f;
    };

    float4 A, B, Cv, D = make_float4(0.f, 0.f, 0.f, 0.f);
    float Am, Aq, Bm, Bq, Cm, Cq, Dm = 0.f, Dq = 0.f;

    A  = loadrow(r0 - 1);
    B  = loadrow(r0);
    Cv = loadrow(r0 + 1);
    halo(A, Am, Aq);
    halo(B, Bm, Bq);
    halo(Cv, Cm, Cq);

#pragma unroll
    for (int s = 0; s < 16; ++s) {
        // Prefetch the next row while computing this one (hides HBM latency).
        if (s < 15) D = loadrow(r0 + s + 2);

        float4 acc;
        acc.x = Am   * w00 + A.x  * w01 + A.y  * w02
              + Bm   * w10 + B.x  * w11 + B.y  * w12
              + Cm   * w20 + Cv.x * w21 + Cv.y * w22;
        acc.y = A.x  * w00 + A.y  * w01 + A.z  * w02
              + B.x  * w10 + B.y  * w11 + B.z  * w12
              + Cv.x * w20 + Cv.y * w21 + Cv.z * w22;
        acc.z = A.y  * w00 + A.z  * w01 + A.w  * w02
              + B.y  * w10 + B.z  * w11 + B.w  * w12
              + Cv.y * w20 + Cv.z * w21 + Cv.w * w22;
        acc.w = A.z  * w00 + A.w  * w01 + Aq   * w02
              + B.z  * w10 + B.w  * w11 + Bq   * w12
              + Cv.z * w20 + Cv.w * w21 + Cq   * w22;

        *(float4*)(op + (r0 + s) * W_SP + col0) = acc;

        if (s < 15) halo(D, Dm, Dq);

        A  = B;  Am = Bm; Aq = Bq;
        B  = Cv; Bm = Cm; Bq = Cq;
        Cv = D;  Cm = Dm; Cq = Dq;
    }
}

extern "C" void kernel_launch(void* const* d_in, const int* in_sizes, int n_in,
                              void* d_out, int out_size, void* d_ws, size_t ws_size,
                              hipStream_t stream) {
    const float* x = (const float*)d_in[0];
    const float* W = (const float*)d_in[1];
    float* out = (float*)d_out;

    const int n_planes = out_size / PLANE;      // 8192
    const int n_blocks = n_planes >> 2;         // 4 planes (waves) per block
    dwconv3x3_reg<<<n_blocks, 256, 0, stream>>>(x, W, out);
}

// Round 3
// 229.587 us; speedup vs baseline: 1.1573x; 1.1573x over previous
//
#include <hip/hip_runtime.h>

// Depthwise 3x3 conv (diagonal-masked dense conv), fp32.
// x: (S*B=32, C=256, H=64, W=64)  W: (256,256,3,3) -> only diag [c,c,:,:] used.
//
// LDS-staged version with PADDED stride (65 floats) to kill the 8-way bank
// conflict of the stride-64 layout:
//   bank = (65*row + col) % 32 = (row + col) % 32; a wave reads 4 consecutive
//   rows at cols == j mod 4 -> rows cover all residues mod 4 -> 32 banks,
//   2 lanes each (2-way aliasing is free on CDNA4, m136).
// Staging writes are 4x ds_write_b32 (odd rows are 16B-unaligned with the
// pad); conflict-free and hidden under the HBM stream.
// One barrier per plane; 4 independent float4 global loads in flight per
// wave; coalesced float4 stores. Pure HBM stream otherwise.

#define C_CH 256
#define H_SP 64
#define W_SP 64
#define LDS_STRIDE 65                    // padded row stride in floats
#define PLANE (H_SP * W_SP)              // 4096 floats = 16 KiB

__global__ __launch_bounds__(256) void dwconv3x3_pad(
    const float* __restrict__ x,
    const float* __restrict__ Wfull,
    float* __restrict__ out)
{
    __shared__ float tile[H_SP * LDS_STRIDE]; // 4160 floats = 16.25 KiB

    const int p = blockIdx.x;            // plane index in [0, 8192)
    const int c = p & (C_CH - 1);        // channel (inner dim of leading index)
    const float* __restrict__ xp = x + (size_t)p * PLANE;
    float* __restrict__ op = out + (size_t)p * PLANE;

    // 9 diagonal weights, block-uniform: W[((c*C + c)*3 + kh)*3 + kw]
    const float* __restrict__ wp = Wfull + (size_t)c * (C_CH + 1) * 9;
    const float w00 = wp[0], w01 = wp[1], w02 = wp[2];
    const float w10 = wp[3], w11 = wp[4], w12 = wp[5];
    const float w20 = wp[6], w21 = wp[7], w22 = wp[8];

    const int t = threadIdx.x;

    // Stage plane into LDS: 4 independent float4 global loads issued first
    // (4 in flight per wave), then scatter to the padded layout as b32s.
    const float4* __restrict__ xv = (const float4*)xp;
    float4 v0 = xv[t];
    float4 v1 = xv[t + 256];
    float4 v2 = xv[t + 512];
    float4 v3 = xv[t + 768];

    {
        const float4 vv[4] = {v0, v1, v2, v3};
#pragma unroll
        for (int i = 0; i < 4; ++i) {
            const int f  = t + i * 256;          // float4 index in plane
            const int h  = f >> 4;               // row
            const int w4 = (f & 15) << 2;        // first column
            float* dst = &tile[h * LDS_STRIDE + w4];
            dst[0] = vv[i].x;
            dst[1] = vv[i].y;
            dst[2] = vv[i].z;
            dst[3] = vv[i].w;
        }
    }
    __syncthreads();

    // Each thread computes 4 output float4s (16 outputs).
#pragma unroll
    for (int i = 0; i < 4; ++i) {
        const int f  = t + i * 256;      // float4 index in plane [0,1024)
        const int h  = f >> 4;           // row
        const int w4 = (f & 15) << 2;    // first column of this float4

        float4 acc = make_float4(0.f, 0.f, 0.f, 0.f);

#pragma unroll
        for (int kh = 0; kh < 3; ++kh) {
            const int hh = h + kh - 1;
            if (hh < 0 || hh >= H_SP) continue;
            const float* row = &tile[hh * LDS_STRIDE];

            const float cm1 = (w4 > 0)         ? row[w4 - 1] : 0.f;
            const float c0  = row[w4];
            const float c1  = row[w4 + 1];
            const float c2  = row[w4 + 2];
            const float c3  = row[w4 + 3];
            const float c4  = (w4 + 4 < W_SP)  ? row[w4 + 4] : 0.f;

            float k0, k1, k2;
            if (kh == 0)      { k0 = w00; k1 = w01; k2 = w02; }
            else if (kh == 1) { k0 = w10; k1 = w11; k2 = w12; }
            else              { k0 = w20; k1 = w21; k2 = w22; }

            acc.x += cm1 * k0 + c0 * k1 + c1 * k2;
            acc.y += c0  * k0 + c1 * k1 + c2 * k2;
            acc.z += c1  * k0 + c2 * k1 + c3 * k2;
            acc.w += c2  * k0 + c3 * k1 + c4 * k2;
        }

        ((float4*)op)[f] = acc;
    }
}

extern "C" void kernel_launch(void* const* d_in, const int* in_sizes, int n_in,
                              void* d_out, int out_size, void* d_ws, size_t ws_size,
                              hipStream_t stream) {
    const float* x = (const float*)d_in[0];
    const float* W = (const float*)d_in[1];
    float* out = (float*)d_out;

    const int n_planes = out_size / PLANE; // 8192
    dwconv3x3_pad<<<n_planes, 256, 0, stream>>>(x, W, out);
}